// Round 9
// baseline (797.448 us; speedup 1.0000x reference)
//
#include <hip/hip_runtime.h>
#include <hip/hip_bf16.h>
#include <cstdint>
#include <cstddef>

// MultiGateMixExperts: fp16 MFMA GEMMs, frag-major layout.
// Frag-major layout: frag(tile16 t, kchunk32 c) = 1KB at ((t*32+c)*64+lane)*16B;
// lane l holds M[row=t*16+(l&15)][k=c*32+(l>>4)*8 .. +7] (fp16).
// R14: break the in-chunk read->MFMA dependency. R13 measured 3000cyc/chunk-
// period ~= LDS(1700) + MFMA(1030) ADDITIVE: COMPUTE read chunk c then MFMA'd
// chunk c (true dep). Fix: triple-buffered LDS (3x24KB=72KB, 2 blocks/CU) +
// two static register sets; each half-iter: STAGE(c+2) -> LOADREGS(next<-c+1)
// -> MFMA(cur=c) -> sync. Loads of c+1 are independent of MFMA(c) -> issue
// under the 512cyc MFMA stretch; lgkm wait lands at next half's top.
// Ledger: LOADREGS src staged 1 half earlier + drained by the intervening
// sync (syncthreads fully drains vmcnt); STAGE targets last read >=2 syncs
// earlier; stage order 0..31 sequential (gs auto-advance); acc K-order
// unchanged -> identical numerics.
// Geometry (R13): block 128x256, 4 waves (2m x 2n), wave 64x128 (4x8 mfma),
// 29 FLOP/LDS-byte. R10 fold retained: f = relu(h_a)·(W2@Wo) + (b2·Wo+bo).
// h0 = sigmoid(x@W1[e]+b1); f = sum_n relu(h0@W2[e]+b2)[n]*v[e][n] (atomics)
// out_i = softmax(x@Wg_i+bg_i) . (f + bo2)

using half8   = __attribute__((ext_vector_type(8))) _Float16;
using floatx4 = __attribute__((ext_vector_type(4))) float;

// ---------------------------------------------------------------- GEMM ------
// ACT: 0=sigmoid (writes C in frag layout), 2=relu+f-dot fused (no C store).
template<int ACT>
__global__ __launch_bounds__(256, 2)
void gemm_kernel(const _Float16* __restrict__ A, const _Float16* __restrict__ Bt,
                 const float* __restrict__ bias, _Float16* __restrict__ C,
                 size_t a_estride,
                 const float* __restrict__ Wo, float* __restrict__ f, int e0)
{
    // 3 x 12KB-halves k-chunk buffers: frags 0..7 = A m-tiles, 8..23 = B
    // n-tiles, 512 halves each, lane-linear. sbuf[0] reused as repack tile.
    __shared__ __align__(16) _Float16 sbuf[3][12288];

    const int tid  = threadIdx.x;
    const int lane = tid & 63;
    const int w    = tid >> 6;      // wave 0..3
    const int wm   = w & 1;         // m-half (64 rows)
    const int wn   = w >> 1;        // n-half (128 cols)

    // --- XCD-aware windowed remap (gridDim = {8, 32*g}) ---
    // per expert: 64 mb x 4 nb = 256 blocks. window = 4 mb x all 4 nb:
    // A-window 1MB + B 2MB ~ L2 per XCD.
    const int flat = blockIdx.x + (blockIdx.y << 3);
    const int xcd  = flat & 7;
    int s = flat >> 3;
    const int g = gridDim.y >> 5;
    int le, mb_base;
    if (g <= 8) {
        const int p = 8 / g;            // XCDs per expert
        le = xcd / p;
        mb_base = (xcd % p) * (64 / p);
    } else {                            // g == 16
        le = (xcd << 1) | (s >> 8);
        s &= 255;
        mb_base = 0;
    }
    const int nb = (s >> 2) & 3;
    const int mb = mb_base + (s >> 4) * 4 + (s & 3);
    const int m0 = mb * 128;
    const int n0 = nb * 256;

    const _Float16* Ae = A    + (size_t)le * a_estride;
    const _Float16* Be = Bt   + (size_t)le * (1024ull * 1024ull);
    const float*    be = bias + (size_t)le * 1024ull;
    _Float16*       Ce = C    + (size_t)le * (8192ull * 1024ull);

    const int mtb_blk = m0 >> 4;          // block's first A m-tile (8 total)
    const int ntb_blk = n0 >> 4;          // block's first B n-tile (16 total)

    // staging: wave w owns frags w*6 .. w*6+5 (24 total: 8 A + 16 B);
    // per-lane global src (+lane*16B), advanced 512 halves per staged chunk.
    const _Float16* gs[6];
#pragma unroll
    for (int u = 0; u < 6; ++u) {
        const int fidx = w * 6 + u;
        gs[u] = (fidx < 8)
            ? (Ae + (size_t)(mtb_blk + fidx) * (32 * 512) + lane * 8)
            : (Be + (size_t)(ntb_blk + (fidx - 8)) * (32 * 512) + lane * 8);
    }

    floatx4 acc[4][8];
#pragma unroll
    for (int i = 0; i < 4; ++i)
#pragma unroll
        for (int j = 0; j < 8; ++j) { floatx4 z = {0.f, 0.f, 0.f, 0.f}; acc[i][j] = z; }

    auto STAGE = [&](_Float16* buf) {
#pragma unroll
        for (int u = 0; u < 6; ++u) {
            __builtin_amdgcn_global_load_lds(
                (const __attribute__((address_space(1))) void*)gs[u],
                (__attribute__((address_space(3))) void*)(buf + (w * 6 + u) * 512),
                16, 0, 0);
            gs[u] += 512;
        }
    };
    auto LOADREGS = [&](half8* a, half8* b, const _Float16* buf) {
#pragma unroll
        for (int i = 0; i < 4; ++i)
            a[i] = *(const half8*)(buf + (wm * 4 + i) * 512 + lane * 8);
#pragma unroll
        for (int j = 0; j < 8; ++j)
            b[j] = *(const half8*)(buf + 4096 + (wn * 8 + j) * 512 + lane * 8);
    };
    auto MFMA32 = [&](const half8* a, const half8* b) {
#pragma unroll
        for (int i = 0; i < 4; ++i)
#pragma unroll
            for (int j = 0; j < 8; ++j)
                acc[i][j] = __builtin_amdgcn_mfma_f32_16x16x32_f16(a[i], b[j], acc[i][j], 0, 0, 0);
    };

    half8 aA[4], bA[8], aB[4], bB[8];
    _Float16* p0 = &sbuf[0][0];   // holds chunk c   (regsA source, consumed)
    _Float16* p1 = &sbuf[1][0];   // holds chunk c+1
    _Float16* p2 = &sbuf[2][0];   // free (target for chunk c+2)

    // ---- prologue: stage chunks 0,1; load regsA <- chunk 0
    STAGE(p0);
    STAGE(p1);
    __syncthreads();              // drains both stages
    LOADREGS(aA, bA, p0);

    // ---- main loop: 15 iters, 2 chunks each (K = 1024 -> 32 chunks of 32)
#pragma unroll 1
    for (int c = 0; c < 30; c += 2) {
        // H1: stage c+2 -> p2; load regsB <- chunk c+1 (p1); MFMA chunk c
        STAGE(p2);
        LOADREGS(aB, bB, p1);
        MFMA32(aA, bA);
        __syncthreads();
        // H2: stage c+3 -> p0 (chunk c dead); load regsA <- chunk c+2 (p2)
        STAGE(p0);
        LOADREGS(aA, bA, p2);
        MFMA32(aB, bB);
        __syncthreads();
        // rotate: (p0,p1,p2) <- (p2, p0, p1)
        _Float16* t = p2; p2 = p1; p1 = p0; p0 = t;
    }
    // tail: regsA = chunk 30; p1 = chunk 31 (staged iter 28 H2, drained)
    LOADREGS(aB, bB, p1);
    MFMA32(aA, bA);
    MFMA32(aB, bB);

    // ----- epilogue; C/D layout: col=lane&15, row=(lane>>4)*4+r -----
    const int q   = lane >> 4;
    const int l15 = lane & 15;
    float bj[8];
#pragma unroll
    for (int j = 0; j < 8; ++j) bj[j] = be[n0 + wn * 128 + j * 16 + l15];

    if (ACT == 2) {
        // f[m, e0+le] += sum_n relu(acc + b2[n]) * v[e0+le, n]
        const float* we = Wo + (size_t)(e0 + le) * 1024;
        float wj[8];
#pragma unroll
        for (int j = 0; j < 8; ++j) wj[j] = we[n0 + wn * 128 + j * 16 + l15];
#pragma unroll
        for (int i = 0; i < 4; ++i) {
            const int mbase = m0 + wm * 64 + i * 16 + q * 4;
#pragma unroll
            for (int r = 0; r < 4; ++r) {
                float sacc = 0.f;
#pragma unroll
                for (int j = 0; j < 8; ++j)
                    sacc += fmaxf(acc[i][j][r] + bj[j], 0.0f) * wj[j];
#pragma unroll
                for (int m = 1; m < 16; m <<= 1) sacc += __shfl_xor(sacc, m, 64);
                if (l15 == 0) atomicAdd(&f[(size_t)(mbase + r) * 16 + (e0 + le)], sacc);
            }
        }
    } else {
        // per-wave repack reusing sbuf[0] (private 3072-half region).
        __syncthreads();                  // all waves past their last LDS read
        _Float16* T = &sbuf[0][0] + w * 3072;   // 16 x 136 halves used
        const int kcg0 = (n0 + wn * 128) >> 5;
#pragma unroll
        for (int i = 0; i < 4; ++i) {
#pragma unroll
            for (int j = 0; j < 8; ++j)
#pragma unroll
                for (int r = 0; r < 4; ++r) {
                    float v = acc[i][j][r] + bj[j];
                    v = 1.0f / (1.0f + __expf(-v));   // ACT==0: sigmoid
                    T[(q * 4 + r) * 136 + j * 16 + l15] = (_Float16)v;
                }
            const int mt = mtb_blk + wm * 4 + i;
#pragma unroll
            for (int kci = 0; kci < 4; ++kci) {
                half8 v8 = *(const half8*)(T + l15 * 136 + kci * 32 + q * 8);
                *(half8*)(Ce + ((size_t)mt * 32 + kcg0 + kci) * 512 + lane * 8) = v8;
            }
        }
    }
}

// --------------------------------------- cast x to fp16 frag layout ---------
__global__ __launch_bounds__(256)
void castx_kernel(const float* __restrict__ x, _Float16* __restrict__ xb)
{
    __shared__ _Float16 tile[64 * 72];   // [m-local][k-local]
    const int k0 = blockIdx.x * 64;
    const int m0 = blockIdx.y * 64;
    const int tid = threadIdx.x;
    const int col4 = (tid & 15) * 4;
    const int rb   = tid >> 4;           // 0..15
#pragma unroll
    for (int p = 0; p < 4; ++p) {
        const int row = rb + p * 16;
        float4 a = *(const float4*)(x + (size_t)(m0 + row) * 1024 + k0 + col4);
        _Float16* d = tile + row * 72 + col4;
        d[0] = (_Float16)a.x; d[1] = (_Float16)a.y; d[2] = (_Float16)a.z; d[3] = (_Float16)a.w;
    }
    __syncthreads();
    const int lane = tid & 63, w = tid >> 6;
    const int l15 = lane & 15, q = lane >> 4;
#pragma unroll
    for (int ff = 0; ff < 2; ++ff) {
        const int fidx = w * 2 + ff;
        const int mi = fidx >> 1, kci = fidx & 1;
        half8 v = *(const half8*)(tile + (mi * 16 + l15) * 72 + kci * 32 + q * 8);
        const size_t mt = (m0 >> 4) + mi, kc = (k0 >> 5) + kci;
        *(half8*)(xb + (mt * 32 + kc) * 512 + lane * 8) = v;
    }
}

// ------------- W1/W2 [d][h] fp32 -> frag-major fp16 (n=h, k=d) --------------
// float4 loads; W2 tiles additionally fold the v = W2@Wo partial dot using
// the fp32 registers (full precision), atomicAdd into v (zeroed by zerof).
__global__ __launch_bounds__(256)
void wtr_kernel(const float* __restrict__ W1, const float* __restrict__ W2,
                _Float16* __restrict__ W1F, _Float16* __restrict__ W2F,
                const float* __restrict__ Wo, float* __restrict__ v)
{
    __shared__ _Float16 tile[64 * 73];   // [k-local][n-local], pad 73
    const int z = blockIdx.z;
    const float* src = (z < 16) ? (W1 + (size_t)z * 1048576ull) : (W2 + (size_t)(z - 16) * 1048576ull);
    _Float16*    dst = (z < 16) ? (W1F + (size_t)z * 1048576ull) : (W2F + (size_t)(z - 16) * 1048576ull);
    const int n0 = blockIdx.x * 64;
    const int k0 = blockIdx.y * 64;
    const int tid = threadIdx.x;
    const int lane = tid & 63, w = tid >> 6;
    const int l15 = lane & 15, q = lane >> 4;

    // vectorized load: 4 x float4 per thread (rows w*4+q+p*16, cols l15*4..+3)
    const int col4 = l15 * 4;
    const int rbase = w * 4 + q;
    float4 a4[4];
#pragma unroll
    for (int p = 0; p < 4; ++p) {
        const int row = rbase + p * 16;
        a4[p] = *(const float4*)(src + (size_t)(k0 + row) * 1024 + n0 + col4);
        _Float16* d = tile + row * 73 + col4;
        d[0] = (_Float16)a4[p].x; d[1] = (_Float16)a4[p].y;
        d[2] = (_Float16)a4[p].z; d[3] = (_Float16)a4[p].w;
    }

    if (z >= 16) {
        // v[e][k0+row] += sum_{n-slice} W2[e][k0+row][n0+c] * Wo[e][n0+c]
        const int e = z - 16;
        const float* wo = Wo + ((size_t)e << 10) + n0;
        float* ve = v + ((size_t)e << 10) + k0;
#pragma unroll
        for (int p = 0; p < 4; ++p) {
            float s = a4[p].x * wo[col4] + a4[p].y * wo[col4 + 1]
                    + a4[p].z * wo[col4 + 2] + a4[p].w * wo[col4 + 3];
            s += __shfl_xor(s, 1, 64);
            s += __shfl_xor(s, 2, 64);
            s += __shfl_xor(s, 4, 64);
            s += __shfl_xor(s, 8, 64);
            if (l15 == 0) atomicAdd(&ve[rbase + p * 16], s);
        }
    }

    __syncthreads();
#pragma unroll
    for (int ff = 0; ff < 2; ++ff) {
        const int fidx = w * 2 + ff;
        const int nti = fidx >> 1, kci = fidx & 1;
        half8 hv;
#pragma unroll
        for (int jj = 0; jj < 8; ++jj)
            hv[jj] = tile[(kci * 32 + q * 8 + jj) * 73 + nti * 16 + l15];
        const size_t nt = (n0 >> 4) + nti, kc = (k0 >> 5) + kci;
        *(half8*)(dst + (nt * 32 + kc) * 512 + lane * 8) = hv;
    }
}

// --------------------------- zero f (0.5MB) + v (64KB), contiguous ----------
__global__ __launch_bounds__(256)
void zerof_kernel(float* __restrict__ f)
{
    const size_t i = ((size_t)blockIdx.x * 256 + threadIdx.x) * 4;
    float4 z = {0.f, 0.f, 0.f, 0.f};
    *(float4*)(f + i) = z;
}

// ----------------- bo2[e] = b2[e].Wo[e] + bo[e]  (16 waves) -----------------
__global__ __launch_bounds__(64)
void prep_bo2_kernel(const float* __restrict__ b2, const float* __restrict__ Wo,
                     const float* __restrict__ bo, float* __restrict__ bo2)
{
    const int e = blockIdx.x;
    const int lane = threadIdx.x;
    const float* br = b2 + ((size_t)e << 10);
    const float* wo = Wo + ((size_t)e << 10);
    float s = 0.f;
#pragma unroll
    for (int t = 0; t < 16; ++t) s += br[t * 64 + lane] * wo[t * 64 + lane];
#pragma unroll
    for (int m = 1; m < 64; m <<= 1) s += __shfl_xor(s, m, 64);
    if (lane == 0) bo2[e] = s + bo[e];
}

// ------------------ gates (fp32, full precision) + softmax + combine --------
__global__ __launch_bounds__(256)
void final_kernel(const float* __restrict__ x,
                  const float* __restrict__ Wg1, const float* __restrict__ bg1,
                  const float* __restrict__ Wg2, const float* __restrict__ bg2,
                  const float* __restrict__ f, const float* __restrict__ bo2,
                  float* __restrict__ out)
{
    const int lane = threadIdx.x & 63;
    const int w    = threadIdx.x >> 6;
    const int b    = blockIdx.x * 8 + w * 2;
    const float* xA = x + (size_t)b * 1024;
    const float* xB = xA + 1024;
    float g1A[16], g2A[16], g1B[16], g2B[16];
#pragma unroll
    for (int e = 0; e < 16; ++e) { g1A[e] = 0.f; g2A[e] = 0.f; g1B[e] = 0.f; g2B[e] = 0.f; }
#pragma unroll 2
    for (int t = 0; t < 16; ++t) {
        const int d = t * 64 + lane;
        const float xa = xA[d];
        const float xb2 = xB[d];
        const float4* w1 = (const float4*)(Wg1 + (size_t)d * 16);
        const float4* w2 = (const float4*)(Wg2 + (size_t)d * 16);
#pragma unroll
        for (int q4 = 0; q4 < 4; ++q4) {
            const float4 c1 = w1[q4];
            const float4 c2 = w2[q4];
#pragma unroll
            for (int c = 0; c < 4; ++c) {
                const int e = q4 * 4 + c;
                const float v1 = (c == 0) ? c1.x : (c == 1) ? c1.y : (c == 2) ? c1.z : c1.w;
                const float v2 = (c == 0) ? c2.x : (c == 1) ? c2.y : (c == 2) ? c2.z : c2.w;
                g1A[e] += xa * v1; g1B[e] += xb2 * v1;
                g2A[e] += xa * v2; g2B[e] += xb2 * v2;
            }
        }
    }
#pragma unroll
    for (int e = 0; e < 16; ++e) {
#pragma unroll
        for (int m = 1; m < 64; m <<= 1) {
            g1A[e] += __shfl_xor(g1A[e], m, 64);
            g2A[e] += __shfl_xor(g2A[e], m, 64);
            g1B[e] += __shfl_xor(g1B[e], m, 64);
            g2B[e] += __shfl_xor(g2B[e], m, 64);
        }
    }
    const float* fbA = f + (size_t)b * 16;
    const float* fbB = fbA + 16;
#pragma unroll
    for (int rr = 0; rr < 2; ++rr) {
        const float* gp1 = rr ? g1B : g1A;
        const float* gp2 = rr ? g2B : g2A;
        const float* fb  = rr ? fbB : fbA;
        float a1[16], a2[16], m1 = -1e30f, m2 = -1e30f;
#pragma unroll
        for (int e = 0; e < 16; ++e) {
            a1[e] = gp1[e] + bg1[e]; m1 = fmaxf(m1, a1[e]);
            a2[e] = gp2[e] + bg2[e]; m2 = fmaxf(m2, a2[e]);
        }
        float s1 = 0.f, s2 = 0.f, o1 = 0.f, o2 = 0.f;
#pragma unroll
        for (int e = 0; e < 16; ++e) {
            a1[e] = __expf(a1[e] - m1); s1 += a1[e];
            a2[e] = __expf(a2[e] - m2); s2 += a2[e];
        }
#pragma unroll
        for (int e = 0; e < 16; ++e) {
            const float fe = fb[e] + bo2[e];
            o1 += a1[e] * fe; o2 += a2[e] * fe;
        }
        if (lane == 0) { out[b + rr] = o1 / s1; out[8192 + b + rr] = o2 / s2; }
    }
}

// ----------------------------------------------------------------------------
extern "C" void kernel_launch(void* const* d_in, const int* in_sizes, int n_in,
                              void* d_out, int out_size, void* d_ws, size_t ws_size,
                              hipStream_t stream)
{
    const float* x   = (const float*)d_in[0];
    const float* W1  = (const float*)d_in[1];
    const float* b1  = (const float*)d_in[2];
    const float* W2  = (const float*)d_in[3];
    const float* b2  = (const float*)d_in[4];
    const float* Wo  = (const float*)d_in[5];
    const float* bo  = (const float*)d_in[6];
    const float* Wg1 = (const float*)d_in[7];
    const float* bg1 = (const float*)d_in[8];
    const float* Wg2 = (const float*)d_in[9];
    const float* bg2 = (const float*)d_in[10];
    float* out = (float*)d_out;

    char* ws = (char*)d_ws;
    _Float16* xb  = (_Float16*)(ws);                         // 16 MB (frag)
    _Float16* W1F = (_Float16*)(ws + 16777216ull);           // 32 MB (frag)
    _Float16* W2F = (_Float16*)(ws + 50331648ull);           // 32 MB (frag)
    float*    f   = (float*)   (ws + 83886080ull);           // 0.5 MB
    float*    v   = (float*)   (ws + 84410368ull);           // 64 KB (after f)
    float*    bo2 = (float*)   (ws + 84475904ull);           // 64 B
    char* hbase = ws + 84475968ull;

    int g = 1;
    const int cands[4] = {16, 8, 4, 2};
    for (int ci = 0; ci < 4; ++ci) {
        const size_t need = 84475968ull + (size_t)cands[ci] * 16777216ull;
        if (need <= ws_size) { g = cands[ci]; break; }
    }
    _Float16* h0 = (_Float16*)hbase;

    // zerof covers f (131072 floats) + v (16384 floats), contiguous: 144 blocks
    zerof_kernel<<<144, 256, 0, stream>>>(f);
    castx_kernel<<<dim3(16, 128), 256, 0, stream>>>(x, xb);
    wtr_kernel<<<dim3(16, 16, 32), 256, 0, stream>>>(W1, W2, W1F, W2F, Wo, v);
    prep_bo2_kernel<<<16, 64, 0, stream>>>(b2, Wo, bo, bo2);

    for (int e0 = 0; e0 < 16; e0 += g) {
        gemm_kernel<0><<<dim3(8, 32 * g), 256, 0, stream>>>(
            xb, W1F + (size_t)e0 * 1048576ull, b1 + (size_t)e0 * 1024, h0, 0,
            nullptr, nullptr, 0);
        gemm_kernel<2><<<dim3(8, 32 * g), 256, 0, stream>>>(
            h0, W2F + (size_t)e0 * 1048576ull, b2 + (size_t)e0 * 1024, h0, 8192ull * 1024ull,
            v, f, e0);
    }
    final_kernel<<<1024, 256, 0, stream>>>(x, Wg1, bg1, Wg2, bg2, f, bo2, out);
}